// Round 2
// baseline (510.523 us; speedup 1.0000x reference)
//
#include <hip/hip_runtime.h>

#define Ff 16
#define Kk 8
#define SIZEk 64
#define PDd 256
#define EDd 768
#define Nn 197
#define BZz 512          // B*F
#define NPROD 64         // producer (keys/KW/ksim) blocks, kernel A
#define NMEAN 1536       // mean blocks: 512 bz * 3 col-chunks of 64 float4
#define RB  256          // route blocks (2 bz each), kernel B
#define ED4 192          // 768/4
#define PD4 64           // 256/4
#define OUT_LOSS ((size_t)32 * 128 * EDd)   // 3145728: ps_loss slot in d_out
#define LOSS_SCALE (1.0f / 32.0f)           // F/BZ = 16/512
#define MAGIC 0x5A17EC0Du                   // != 0xAAAAAAAA poison, != 0

__device__ __forceinline__ void acc4(float4& s, float4 a) {
    s.x += a.x; s.y += a.y; s.z += a.z; s.w += a.w;
}

// ===================== Kernel A: means + producers ==========================
// Blocks 0..63: producers (keys[s]=l2norm(pv[s]); KW[s]=keys[s]@Wout^T; ksim).
//   They spin only on EACH OTHER via slots[]; being the first 64 dispatched of
//   1600 they are always co-resident => deadlock-free, ~0 spin.
// Blocks 64..1599: mean blocks. Block owns (bz, col-chunk c3): columns
//   [c3*64, c3*64+64) in float4 units, ALL 197 rows. 256 threads = 64 cols x
//   4 row-groups; each thread strides rows by 4, unroll 8 => 32 KB in flight
//   per block; grid 1600 => ~75% occupancy => x-read runs near HBM ceiling.
//   Exclusive column ownership => no atomics, direct xf write after LDS reduce.
__global__ __launch_bounds__(256, 4) void k_mean(const float4* __restrict__ x,
                                                 const float* __restrict__ Wout,
                                                 const float* __restrict__ pv,
                                                 float* __restrict__ keys,
                                                 float* __restrict__ KW,
                                                 unsigned* __restrict__ slots,
                                                 float4* __restrict__ xf,
                                                 float* __restrict__ out) {
    int blk = blockIdx.x, t = threadIdx.x;

    if (blk < NPROD) {
        // ================= producer block s =================
        __shared__ float ks[PDd];
        __shared__ float redp[4];
        __shared__ float s_norm;
        int s = blk;
        float v  = pv[(size_t)s * PDd + t];
        float sq = v * v;
        for (int o = 32; o > 0; o >>= 1) sq += __shfl_down(sq, o);
        if ((t & 63) == 0) redp[t >> 6] = sq;
        __syncthreads();
        if (t == 0) s_norm = fmaxf(sqrtf(redp[0] + redp[1] + redp[2] + redp[3]), 1e-12f);
        __syncthreads();
        float kv = v / s_norm;
        ks[t] = kv;
        keys[(size_t)s * PDd + t] = kv;
        __syncthreads();

        // KW row s: 768 outputs, 3 per thread
        for (int r = 0; r < 3; r++) {
            int e = t + 256 * r;
            const float4* w  = (const float4*)(Wout + (size_t)e * PDd);
            const float4* k4 = (const float4*)ks;
            float d = 0.f;
            for (int i = 0; i < PD4; i++) {
                float4 wv = w[i]; float4 kvv = k4[i];
                d += wv.x * kvv.x + wv.y * kvv.y + wv.z * kvv.z + wv.w * kvv.w;
            }
            KW[(size_t)s * EDd + e] = d;
        }
        if (s == 0 && t == 0) out[OUT_LOSS] = 0.0f;   // ordered before slot-0 release
        __syncthreads();   // vmcnt(0) drain before barrier: stores visible
        if (t == 0)
            __hip_atomic_store(&slots[s], MAGIC, __ATOMIC_RELEASE, __HIP_MEMORY_SCOPE_AGENT);

        // ---- ksim row s (needs ALL keys; producers co-resident => ~0 spin) --
        if (t < SIZEk) {
            while (__hip_atomic_load(&slots[t], __ATOMIC_ACQUIRE, __HIP_MEMORY_SCOPE_AGENT)
                   != MAGIC)
                __builtin_amdgcn_s_sleep(8);
        }
        __syncthreads();
        if (t < SIZEk) {
            const float4* a = (const float4*)(keys + (size_t)s * PDd);
            const float4* b = (const float4*)(keys + (size_t)t * PDd);
            float d = 0.f;
            for (int c = 0; c < PD4; c++) {
                float4 av = a[c], bv = b[c];
                d += av.x * bv.x + av.y * bv.y + av.z * bv.z + av.w * bv.w;
            }
            float vv = fabsf(d - (s == t ? 1.0f : 0.0f));
            for (int o = 32; o > 0; o >>= 1) vv += __shfl_down(vv, o);
            if (t == 0) atomicAdd(out + OUT_LOSS, vv * LOSS_SCALE);
        }
        return;
    }

    // ================= mean block: (bz, c3) =================
    int m  = blk - NPROD;        // 0..1535
    int bz = m / 3;
    int c3 = m - bz * 3;
    int c = t & 63, g = t >> 6;  // col-in-chunk, row-group (wave-uniform)
    const int STR = 4 * ED4;     // row stride (x4 row groups) in float4
    const float4* p = x + ((size_t)bz * Nn + g) * ED4 + c3 * 64 + c;
    float4 s = make_float4(0.f, 0.f, 0.f, 0.f);
    int cnt = (Nn - g + 3) >> 2; // 50,49,49,49
    int j = 0;
    for (; j + 8 <= cnt; j += 8) {
        float4 a0 = p[(size_t)(j + 0) * STR], a1 = p[(size_t)(j + 1) * STR];
        float4 a2 = p[(size_t)(j + 2) * STR], a3 = p[(size_t)(j + 3) * STR];
        float4 a4 = p[(size_t)(j + 4) * STR], a5 = p[(size_t)(j + 5) * STR];
        float4 a6 = p[(size_t)(j + 6) * STR], a7 = p[(size_t)(j + 7) * STR];
        acc4(s, a0); acc4(s, a1); acc4(s, a2); acc4(s, a3);
        acc4(s, a4); acc4(s, a5); acc4(s, a6); acc4(s, a7);
    }
    for (; j < cnt; j++) acc4(s, p[(size_t)j * STR]);

    __shared__ float4 part[4][64];
    part[g][c] = s;
    __syncthreads();
    if (t < 64) {
        float4 a = part[0][t], b = part[1][t], d2 = part[2][t], e = part[3][t];
        const float inv = 1.0f / (float)Nn;
        float4 r;
        r.x = (a.x + b.x + d2.x + e.x) * inv;
        r.y = (a.y + b.y + d2.y + e.y) * inv;
        r.z = (a.z + b.z + d2.z + e.z) * inv;
        r.w = (a.w + b.w + d2.w + e.w) * inv;
        xf[(size_t)bz * ED4 + c3 * 64 + t] = r;
    }
}

// ===================== Kernel B: route (2 bz per block) =====================
// Kernel boundary = sync: keys/KW/xf complete, no polling needed.
__global__ __launch_bounds__(256, 2) void k_route(const float* __restrict__ Win,
                                                  const float* __restrict__ keys,
                                                  const float* __restrict__ KW,
                                                  const float4* __restrict__ xf,
                                                  float* __restrict__ out) {
    int blk = blockIdx.x, t = threadIdx.x;
    __shared__ float xs[2][EDd];     // xf for both rows (as 192 float4 each)
    __shared__ float qs[2][PDd];     // normalized query rows
    __shared__ int   s_idx[2][Kk];
    __shared__ float s_sim[2][Kk];
    __shared__ float red[2][4];
    int bz0 = blk * 2;

    // ---- phase 1: load both xf rows (contiguous 3 KB, one coalesced pass) --
    {
        const float4* src = xf + (size_t)bz0 * ED4;
        for (int i = t; i < 2 * ED4; i += 256)
            ((float4*)xs)[i] = src[i];
    }
    __syncthreads();

    // ---- phase 2: query p=t for both rows (one W_in read, two dots) ----
    {
        const float4* w  = (const float4*)Win + (size_t)t * ED4;
        const float4* x0 = (const float4*)xs[0];
        const float4* x1 = (const float4*)xs[1];
        float d0a = 0.f, d0b = 0.f, d1a = 0.f, d1b = 0.f;
        for (int i = 0; i < ED4; i += 2) {           // split accumulators
            float4 w0 = w[i],      w1 = w[i + 1];
            float4 u0 = x0[i],     u1 = x1[i];
            float4 u2 = x0[i + 1], u3 = x1[i + 1];
            d0a += w0.x * u0.x + w0.y * u0.y + w0.z * u0.z + w0.w * u0.w;
            d1a += w0.x * u1.x + w0.y * u1.y + w0.z * u1.z + w0.w * u1.w;
            d0b += w1.x * u2.x + w1.y * u2.y + w1.z * u2.z + w1.w * u2.w;
            d1b += w1.x * u3.x + w1.y * u3.y + w1.z * u3.z + w1.w * u3.w;
        }
        float d0 = d0a + d0b, d1 = d1a + d1b;
        float sq0 = d0 * d0, sq1 = d1 * d1;
        for (int o = 32; o > 0; o >>= 1) {
            sq0 += __shfl_down(sq0, o);
            sq1 += __shfl_down(sq1, o);
        }
        if ((t & 63) == 0) { red[0][t >> 6] = sq0; red[1][t >> 6] = sq1; }
        __syncthreads();
        float n0 = fmaxf(sqrtf(red[0][0] + red[0][1] + red[0][2] + red[0][3]), 1e-12f);
        float n1 = fmaxf(sqrtf(red[1][0] + red[1][1] + red[1][2] + red[1][3]), 1e-12f);
        qs[0][t] = d0 / n0;
        qs[1][t] = d1 / n1;
    }
    __syncthreads();

    // ---- phase 3: sim + top-8; wave 0 -> row 0, wave 1 -> row 1 ----
    if (t < 2 * SIZEk) {
        int row  = t >> 6;           // wave id
        int lane = t & 63;
        const float4* kr = (const float4*)(keys + (size_t)lane * PDd);
        const float4* qr = (const float4*)qs[row];
        float d = 0.f;
        for (int c = 0; c < PD4; c++) {
            float4 a = kr[c], b = qr[c];
            d += a.x * b.x + a.y * b.y + a.z * b.z + a.w * b.w;
        }
        float v = d;
        for (int k = 0; k < Kk; k++) {
            float mv = v; int mi = lane;
            for (int o = 32; o > 0; o >>= 1) {
                float ov = __shfl_xor(mv, o);
                int   oi = __shfl_xor(mi, o);
                if (ov > mv || (ov == mv && oi < mi)) { mv = ov; mi = oi; }
            }
            if (lane == 0) { s_idx[row][k] = mi; s_sim[row][k] = mv; }
            if (lane == mi) v = -3e38f;  // remove winner (tie -> lowest idx)
        }
    }
    __syncthreads();

    // ---- phase 4: recon + diff for both rows (thread t == d) ----
    {
        float r0 = 0.f, r1 = 0.f;
        for (int k = 0; k < Kk; k++) {
            r0 += s_sim[0][k] * keys[(size_t)s_idx[0][k] * PDd + t];
            r1 += s_sim[1][k] * keys[(size_t)s_idx[1][k] * PDd + t];
        }
        float e0 = r0 - qs[0][t];
        float e1 = r1 - qs[1][t];
        float sq = e0 * e0 + e1 * e1;
        for (int o = 32; o > 0; o >>= 1) sq += __shfl_down(sq, o);
        if ((t & 63) == 0) red[0][t >> 6] = sq;
        __syncthreads();
        if (t == 0) atomicAdd(out + OUT_LOSS,
                              (red[0][0] + red[0][1] + red[0][2] + red[0][3]) * LOSS_SCALE);
    }

    // ---- phase 5: 16 contiguous out rows (bz0*K .. bz0*K+15) = KW[idx] gather --
    float4* orow = (float4*)out + (size_t)bz0 * Kk * ED4;
    for (int i = t; i < 2 * Kk * ED4; i += 256) {
        int which = i / ED4;         // 0..15
        int e4    = i - which * ED4;
        int idx   = s_idx[which >> 3][which & 7];
        orow[i] = ((const float4*)(KW + (size_t)idx * EDd))[e4];
    }
}

extern "C" void kernel_launch(void* const* d_in, const int* in_sizes, int n_in,
                              void* d_out, int out_size, void* d_ws, size_t ws_size,
                              hipStream_t stream) {
    const float* x    = (const float*)d_in[0];   // [32, 16*197, 768]
    const float* Win  = (const float*)d_in[1];   // [256, 768]
    const float* Wout = (const float*)d_in[2];   // [768, 256]
    const float* pv   = (const float*)d_in[3];   // [64, 1, 256]
    float* out = (float*)d_out;                  // [32,128,768] ++ [1]
    float* ws  = (float*)d_ws;

    float*    keys  = ws;                        // 64*256  = 16384 floats
    float*    KW    = ws + 16384;                // 64*768  = 49152 floats
    unsigned* slots = (unsigned*)(ws + 65536);   // 64 flags (poisoned != MAGIC each launch)
    float*    xf    = ws + 65600;                // 512*768 = 393216 floats

    k_mean<<<NPROD + NMEAN, 256, 0, stream>>>((const float4*)x, Wout, pv,
                                              keys, KW, slots, (float4*)xf, out);
    k_route<<<RB, 256, 0, stream>>>(Win, keys, KW, (const float4*)xf, out);
}